// Round 13
// baseline (21380.107 us; speedup 1.0000x reference)
//
#include <hip/hip_runtime.h>

// GRU T=512 B=256 D=512 H=512 O=256
// R13: group-of-TWO exchange. 32 wgs x 1024 threads (16 waves); wg owns
// 16 rows x 256 cols/gate; U register-resident (192 VGPR/lane). Per step:
// publish own half (scattered 2B AGENT, R3-proven) -> 1 flag -> poll partner
// flag -> load remote HALF (8KB coalesced); own half stays in LDS. x@W folded
// as bubbles (R11 proved bubbles are free). No prepass. FC fused. All spins
// bounded; all primitives AGENT-scope (proven since R3).

#define T_ 512
#define B_ 256
#define D_ 512
#define H_ 512
#define O_ 256

#define NWG 32
#define ROWS 16

typedef __attribute__((ext_vector_type(8))) short short8;
typedef __attribute__((ext_vector_type(4))) float f32x4;

__device__ __forceinline__ unsigned short f2bf(float f) {
  unsigned u = __float_as_uint(f);
  u = (u + 0x7FFFu + ((u >> 16) & 1u)) >> 16;   // RNE
  return (unsigned short)u;
}
__device__ __forceinline__ float bf2f(unsigned short h) {
  return __uint_as_float(((unsigned)h) << 16);
}

// ---- prep: transpose weights to N-major bf16, combine biases, zero flags
__global__ void prep_kernel(const float* wz, const float* uz,
                            const float* wr, const float* ur,
                            const float* wh, const float* uh,
                            const float* bz, const float* ubz,
                            const float* br, const float* ubr,
                            const float* bh, const float* ubh,
                            unsigned short* WT, unsigned short* UT,
                            float* cb, int* bar)
{
  int idx = blockIdx.x * 256 + threadIdx.x;
  if (idx < 1536 * 512) {
    int n = idx >> 9;
    int k = idx & 511;
    int g = n >> 9;
    int c = n & 511;
    const float* w = (g == 0) ? wz : (g == 1) ? wr : wh;
    const float* u = (g == 0) ? uz : (g == 1) ? ur : uh;
    WT[idx] = f2bf(w[k * H_ + c]);   // WT[n][k] = W[k][n]
    UT[idx] = f2bf(u[k * H_ + c]);
  }
  if (idx < 1536) {
    int g = idx >> 9, c = idx & 511;
    const float* b  = (g == 0) ? bz  : (g == 1) ? br  : bh;
    const float* ub = (g == 0) ? ubz : (g == 1) ? ubr : ubh;
    cb[idx] = b[c] + ub[c];
  }
  if (idx < 4096) bar[idx] = 0;   // 16 groups x 2 slots x 32-int stride
}

// ---- persistent scan (+ fused FC). 1024 threads, 16 waves.
__global__ __launch_bounds__(1024, 1) void gru_scan(
    const float* __restrict__ x,
    const unsigned short* __restrict__ WT,
    const unsigned short* __restrict__ UT,
    const float* __restrict__ cb,
    unsigned short* hbuf, unsigned short* rhbuf, int* bar,
    const float* __restrict__ fcw, const float* __restrict__ fcb,
    float* __restrict__ out)
{
  __shared__ __align__(16) unsigned short x_lds[2][ROWS][520];
  __shared__ __align__(16) unsigned short h_lds[ROWS][520];
  __shared__ __align__(16) unsigned short rh_lds[ROWS][520];

  const int tid = threadIdx.x;
  const int wid = tid >> 6;       // 0..15
  const int lane = tid & 63;
  const int l16 = lane & 15;
  const int lhi = lane >> 4;

  const int wgid = blockIdx.x;    // 0..31
  const int bg = wgid >> 1;       // 0..15
  const int cg = wgid & 1;        // 0..1
  const int r0 = bg * ROWS;
  const int c0 = cg * 256;
  const int oc0 = c0 ^ 256;       // partner's half

  int* slots  = bar + bg * 256;   // 2 slots x 32-int stride
  int* myslot = slots + cg * 32;

  const int ct = c0 + wid * 16;   // this wave's 16-col tile (per gate)
  const int gcz = ct + l16;
  const unsigned short* WTz = WT + (size_t)(ct)        * 512;
  const unsigned short* WTr = WT + (size_t)(512 + ct)  * 512;
  const unsigned short* WTh = WT + (size_t)(1024 + ct) * 512;
  const unsigned short* UTz = UT + (size_t)(ct)        * 512;
  const unsigned short* UTr = UT + (size_t)(512 + ct)  * 512;
  const unsigned short* UTh = UT + (size_t)(1024 + ct) * 512;
  const float cbz = cb[gcz];
  const float cbr = cb[512 + gcz];
  const float cbh = cb[1024 + gcz];

  // U -> registers (48 short8 = 192 VGPR)
  short8 uzr[16], urr[16], uhr[16];
  #pragma unroll
  for (int k = 0; k < 16; ++k) {
    const int off = l16 * 512 + k * 32 + lhi * 8;
    uzr[k] = *(const short8*)(UTz + off);
    urr[k] = *(const short8*)(UTr + off);
    uhr[k] = *(const short8*)(UTh + off);
  }

  // exchange geometry: 1 x 8B per thread covers a 16x256 bf16 half
  const int prow = tid >> 6;        // 0..15
  const int pchk = (tid & 63) * 4;  // 0..252

  // ---- prologue: x_0 -> LDS, x_1 -> regs, h_lds = 0, x_0@W ----
  float4 xr4[2];
  {
    const float4* xs = (const float4*)(x + (size_t)r0 * D_);
    #pragma unroll
    for (int i = 0; i < 2; ++i) {
      int g = tid + i * 1024;
      int row = g >> 7, c4 = g & 127;
      float4 v = xs[row * 128 + c4];
      unsigned short tmp[4] = { f2bf(v.x), f2bf(v.y), f2bf(v.z), f2bf(v.w) };
      *(unsigned long long*)&x_lds[0][row][c4 * 4] = *(unsigned long long*)tmp;
      *(unsigned long long*)&h_lds[row][c4 * 4] = 0ull;
    }
    const float4* xs1 = (const float4*)(x + ((size_t)B_ + r0) * D_);
    #pragma unroll
    for (int i = 0; i < 2; ++i) {
      int g = tid + i * 1024;
      xr4[i] = xs1[(g >> 7) * 128 + (g & 127)];
    }
  }
  __syncthreads();

  f32x4 xzc = {0.f,0.f,0.f,0.f}, xrc = {0.f,0.f,0.f,0.f}, xhc = {0.f,0.f,0.f,0.f};
  {
    const unsigned short* xrow = &x_lds[0][l16][0];
    #pragma unroll
    for (int k = 0; k < 16; ++k) {
      int ko = k * 32 + lhi * 8;
      short8 ax = *(const short8*)(xrow + ko);
      int boff = l16 * 512 + ko;
      short8 wz = *(const short8*)(WTz + boff);
      short8 wr = *(const short8*)(WTr + boff);
      short8 wh = *(const short8*)(WTh + boff);
      xzc = __builtin_amdgcn_mfma_f32_16x16x32_bf16(ax, wz, xzc, 0, 0, 0);
      xrc = __builtin_amdgcn_mfma_f32_16x16x32_bf16(ax, wr, xrc, 0, 0, 0);
      xhc = __builtin_amdgcn_mfma_f32_16x16x32_bf16(ax, wh, xhc, 0, 0, 0);
    }
  }

  for (int t = 0; t < T_; ++t) {
    const int p = t & 1;
    // ---- phase A: h@Uz, h@Ur (32 MFMA) ----
    f32x4 accz = {0.f,0.f,0.f,0.f};
    f32x4 accr = {0.f,0.f,0.f,0.f};
    {
      const unsigned short* hrow = &h_lds[l16][0];
      #pragma unroll
      for (int k = 0; k < 16; ++k) {
        short8 ah = *(const short8*)(hrow + k * 32 + lhi * 8);
        accz = __builtin_amdgcn_mfma_f32_16x16x32_bf16(ah, uzr[k], accz, 0, 0, 0);
        accr = __builtin_amdgcn_mfma_f32_16x16x32_bf16(ah, urr[k], accr, 0, 0, 0);
      }
    }
    // epi A: z,(1-z)h in regs; rh -> rh_lds own + scattered publish (R3-proven)
    f32x4 z4, gh4;
    #pragma unroll
    for (int i = 0; i < 4; ++i) {
      int lrow = lhi * 4 + i;
      float h_old = bf2f(h_lds[lrow][gcz]);
      float zv = 1.f / (1.f + __expf(-(accz[i] + xzc[i] + cbz)));
      float rv = 1.f / (1.f + __expf(-(accr[i] + xrc[i] + cbr)));
      z4[i]  = zv;
      gh4[i] = (1.f - zv) * h_old;
      unsigned short rb = f2bf(rv * h_old);
      rh_lds[lrow][gcz] = rb;
      __hip_atomic_store(rhbuf + (size_t)(r0 + lrow) * H_ + gcz, rb,
                         __ATOMIC_RELAXED, __HIP_MEMORY_SCOPE_AGENT);
    }
    // stage x_{t+1} regs -> LDS (other buffer)
    #pragma unroll
    for (int i = 0; i < 2; ++i) {
      int g = tid + i * 1024;
      float4 v = xr4[i];
      unsigned short tmp[4] = { f2bf(v.x), f2bf(v.y), f2bf(v.z), f2bf(v.w) };
      *(unsigned long long*)&x_lds[p ^ 1][g >> 7][(g & 127) * 4] = *(unsigned long long*)tmp;
    }
    asm volatile("s_waitcnt vmcnt(0)" ::: "memory");   // publishes drained (per wave)
    __syncthreads();                                   // SA
    if (tid == 0)
      __hip_atomic_store(myslot, 2 * t + 1, __ATOMIC_RELAXED, __HIP_MEMORY_SCOPE_AGENT);

    // bubbles: xz_next, xr_next
    f32x4 xzn = {0.f,0.f,0.f,0.f}, xrn = {0.f,0.f,0.f,0.f}, xhn = {0.f,0.f,0.f,0.f};
    {
      const unsigned short* xrow = &x_lds[p ^ 1][l16][0];
      #pragma unroll
      for (int k = 0; k < 16; ++k) {
        int ko = k * 32 + lhi * 8;
        short8 ax = *(const short8*)(xrow + ko);
        short8 wz = *(const short8*)(WTz + l16 * 512 + ko);
        short8 wr = *(const short8*)(WTr + l16 * 512 + ko);
        xzn = __builtin_amdgcn_mfma_f32_16x16x32_bf16(ax, wz, xzn, 0, 0, 0);
        xrn = __builtin_amdgcn_mfma_f32_16x16x32_bf16(ax, wr, xrn, 0, 0, 0);
      }
    }
    // poll partner (bounded)
    if (tid < 2) {
      int lim = 0;
      while (__hip_atomic_load(slots + tid * 32, __ATOMIC_RELAXED,
                               __HIP_MEMORY_SCOPE_AGENT) < 2 * t + 1)
        { if (++lim > (1 << 16)) break; }
    }
    __syncthreads();                                   // SB
    // consume remote rh half (coalesced 8B/thread)
    {
      unsigned long long v = __hip_atomic_load(
          (const unsigned long long*)(rhbuf + (size_t)(r0 + prow) * H_ + oc0 + pchk),
          __ATOMIC_RELAXED, __HIP_MEMORY_SCOPE_AGENT);
      *(unsigned long long*)&rh_lds[prow][oc0 + pchk] = v;
    }
    __syncthreads();                                   // SC

    // ---- phase B: rh@Uh (16 MFMA) ----
    f32x4 acc2 = {0.f,0.f,0.f,0.f};
    {
      const unsigned short* rrow = &rh_lds[l16][0];
      #pragma unroll
      for (int k = 0; k < 16; ++k) {
        short8 ar = *(const short8*)(rrow + k * 32 + lhi * 8);
        acc2 = __builtin_amdgcn_mfma_f32_16x16x32_bf16(ar, uhr[k], acc2, 0, 0, 0);
      }
    }
    // epi B: h_new -> h_lds own + scattered publish
    #pragma unroll
    for (int i = 0; i < 4; ++i) {
      int lrow = lhi * 4 + i;
      float hh = tanhf(acc2[i] + xhc[i] + cbh);
      float hn = gh4[i] + z4[i] * hh;
      unsigned short hb = f2bf(hn);
      h_lds[lrow][gcz] = hb;
      __hip_atomic_store(hbuf + (size_t)(r0 + lrow) * H_ + gcz, hb,
                         __ATOMIC_RELAXED, __HIP_MEMORY_SCOPE_AGENT);
    }
    asm volatile("s_waitcnt vmcnt(0)" ::: "memory");
    __syncthreads();                                   // SD
    if (tid == 0)
      __hip_atomic_store(myslot, 2 * t + 2, __ATOMIC_RELAXED, __HIP_MEMORY_SCOPE_AGENT);

    // prefetch x_{t+2}; bubble xh_next
    {
      int tn = (t + 2 < T_) ? (t + 2) : (T_ - 1);
      const float4* xs = (const float4*)(x + ((size_t)tn * B_ + r0) * D_);
      #pragma unroll
      for (int i = 0; i < 2; ++i) {
        int g = tid + i * 1024;
        xr4[i] = xs[(g >> 7) * 128 + (g & 127)];
      }
    }
    {
      const unsigned short* xrow = &x_lds[p ^ 1][l16][0];
      #pragma unroll
      for (int k = 0; k < 16; ++k) {
        int ko = k * 32 + lhi * 8;
        short8 ax = *(const short8*)(xrow + ko);
        short8 wh = *(const short8*)(WTh + l16 * 512 + ko);
        xhn = __builtin_amdgcn_mfma_f32_16x16x32_bf16(ax, wh, xhn, 0, 0, 0);
      }
    }
    if (tid < 2) {
      int lim = 0;
      while (__hip_atomic_load(slots + tid * 32, __ATOMIC_RELAXED,
                               __HIP_MEMORY_SCOPE_AGENT) < 2 * t + 2)
        { if (++lim > (1 << 16)) break; }
    }
    __syncthreads();                                   // SE
    // consume remote h half
    {
      unsigned long long v = __hip_atomic_load(
          (const unsigned long long*)(hbuf + (size_t)(r0 + prow) * H_ + oc0 + pchk),
          __ATOMIC_RELAXED, __HIP_MEMORY_SCOPE_AGENT);
      *(unsigned long long*)&h_lds[prow][oc0 + pchk] = v;
    }
    xzc = xzn; xrc = xrn; xhc = xhn;
    __syncthreads();                                   // SF
  }

  // ---- fused FC epilogue: h_lds holds full h_T (16 rows x 512 cols) ----
  if (wid < 8) {
    const int cfc = cg * 128 + wid * 16 + l16;   // 0..255
    f32x4 acc = {0.f,0.f,0.f,0.f};
    const unsigned short* hrow = &h_lds[l16][0];
    #pragma unroll
    for (int k0 = 0; k0 < 512; k0 += 32) {
      int ko = k0 + lhi * 8;
      short8 ah = *(const short8*)(hrow + ko);
      short8 bw;
      #pragma unroll
      for (int j = 0; j < 8; ++j)
        bw[j] = (short)f2bf(fcw[(size_t)(ko + j) * O_ + cfc]);
      acc = __builtin_amdgcn_mfma_f32_16x16x32_bf16(ah, bw, acc, 0, 0, 0);
    }
    float bb = fcb[cfc];
    #pragma unroll
    for (int i = 0; i < 4; ++i)
      out[(size_t)(r0 + lhi * 4 + i) * O_ + cfc] = acc[i] + bb;
  }
}

extern "C" void kernel_launch(void* const* d_in, const int* in_sizes, int n_in,
                              void* d_out, int out_size, void* d_ws, size_t ws_size,
                              hipStream_t stream)
{
  const float* x    = (const float*)d_in[0];
  const float* w_z  = (const float*)d_in[1];
  const float* b_z  = (const float*)d_in[2];
  const float* u_z  = (const float*)d_in[3];
  const float* ub_z = (const float*)d_in[4];
  const float* w_r  = (const float*)d_in[5];
  const float* b_r  = (const float*)d_in[6];
  const float* u_r  = (const float*)d_in[7];
  const float* ub_r = (const float*)d_in[8];
  const float* w_h  = (const float*)d_in[9];
  const float* b_h  = (const float*)d_in[10];
  const float* u_h  = (const float*)d_in[11];
  const float* ub_h = (const float*)d_in[12];
  const float* fc_w = (const float*)d_in[13];
  const float* fc_b = (const float*)d_in[14];
  float* out = (float*)d_out;

  char* ws = (char*)d_ws;
  unsigned short* WT = (unsigned short*)ws;  ws += (size_t)1536 * 512 * 2;
  unsigned short* UT = (unsigned short*)ws;  ws += (size_t)1536 * 512 * 2;
  float* cb = (float*)ws;                    ws += 1536 * 4;
  unsigned short* hbuf = (unsigned short*)ws;  ws += (size_t)B_ * H_ * 2;
  unsigned short* rhbuf = (unsigned short*)ws; ws += (size_t)B_ * H_ * 2;
  ws = (char*)(((size_t)ws + 255) & ~(size_t)255);
  int* bar = (int*)ws;

  prep_kernel<<<3072, 256, 0, stream>>>(w_z, u_z, w_r, u_r, w_h, u_h,
                                        b_z, ub_z, b_r, ub_r, b_h, ub_h,
                                        WT, UT, cb, bar);
  gru_scan<<<NWG, 1024, 0, stream>>>(x, WT, UT, cb, hbuf, rhbuf, bar,
                                     fc_w, fc_b, out);
}